// Round 11
// baseline (218.329 us; speedup 1.0000x reference)
//
#include <hip/hip_runtime.h>

// FWEnergyGAD: element-wise double-well energy + forces + GAD direction +
// 2x2 Hessian eigendecomposition (closed form).
//
// Outputs concatenated flat in return order (n = B):
//   [0,     n)   energy
//   [n,    3n)   forces      (B,2)
//   [3n,   5n)   energy_grad (B,2)
//   [5n,   9n)   hessian     (B,2,2)
//   [9n,  10n)   eigenval 0  (smaller)
//   [10n, 11n)   eigenval 1  (larger)
//
// v10: FLAT SWEEP x GRID-STRIDE (the fill's exact cell). Ledger:
//   v1/v4/v6 (1pt/thread, one-shot, full occ)         ~88-90 us
//   v2/v3/v5 (fat threads / persistent hybrid)        ~93-97
//   v8 (phase-separated R/W, full occ)                ~92
//   v7 (flat sweep, ONE-SHOT 45K blocks)              ~104
//   v9 (chunked frontiers, grid 256)                  ~106
// while the harness fill does 738 MB at 6.7 TB/s in this same timed
// region. Falsified individually: ILP, burst size, NT, ALU cost,
// persistence, stream count, R/W mixing, low occupancy alone, chunked
// frontiers. The fill's remaining distinguishing property: grid-stride
// over a FLAT range -> all resident waves' next stores land in one ~2MB
// moving window that sweeps the buffer in address order. v10 = v7's body
// (one thread -> one output float4, region decoded from flat index,
// inputs recomputed per region) inside a grid-stride loop at 512 blocks
// (8 waves/CU): six globally-sequential region sweeps, each ONE
// contiguous write stream + small sequential input-read frontier
// (L2/MALL-resident, input re-read ~2.5x = ~85MB extra reads, absorbed).
// Clean one-variable A/B vs v7: one-shot grid -> grid-stride 512.

typedef float f2v __attribute__((ext_vector_type(2)));
typedef float f4v __attribute__((ext_vector_type(4)));

#define BLOCK 256
#define GRID 512

namespace {

struct P { float u, v, uu, vv, a, b; };

__device__ __forceinline__ P pre(float px, float py) {
    P o;
    o.u = px - 0.5f;
    o.v = py - 0.5f;
    o.uu = o.u * o.u;
    o.vv = o.v * o.v;
    o.a = o.uu - 1.0f;
    o.b = o.vv - 1.0f;
    return o;
}

__device__ __forceinline__ float energyf(const P& p) {
    return p.a * p.a + p.b * p.b + 0.1f * p.u * p.v;
}

__device__ __forceinline__ f2v forcef(const P& p) {
    f2v f;
    f.x = -(4.0f * p.u * p.a + 0.1f * p.v);
    f.y = -(4.0f * p.v * p.b + 0.1f * p.u);
    return f;
}

__device__ __forceinline__ f2v eigf(const P& p) {   // (l0, l1)
    float hxx = 12.0f * p.uu - 4.0f;
    float hyy = 12.0f * p.vv - 4.0f;
    float d = 0.5f * (hxx - hyy);
    float m = 0.5f * (hxx + hyy);
    float r = __builtin_amdgcn_sqrtf(d * d + 0.01f);   // >= 0.1
    f2v e; e.x = m - r; e.y = m + r;
    return e;
}

__device__ __forceinline__ f2v gradf(const P& p) {
    float hxx = 12.0f * p.uu - 4.0f;
    float hyy = 12.0f * p.vv - 4.0f;
    float d = 0.5f * (hxx - hyy);
    float m = 0.5f * (hxx + hyy);
    float r = __builtin_amdgcn_sqrtf(d * d + 0.01f);
    float l0 = m - r, l1 = m + r;
    f2v f = forcef(p);
    // Eigenvector branch avoids fp32 cancellation (|d| up to ~380 vs
    // hxy = 0.1; the wrong branch computes r-|d|).
    bool pos = (d >= 0.0f);
    float wx = pos ? 0.1f : (d - r);
    float wy = pos ? -(d + r) : 0.1f;
    float n2 = wx * wx + wy * wy;            // >= 0.01
    float fd = f.x * wx + f.y * wy;
    float s = (2.0f * fd) * __builtin_amdgcn_rcpf(n2);
    float gx = -f.x + s * wx;
    float gy = -f.y + s * wy;
    float g2 = gx * gx + gy * gy;            // gmag^2; gmag<1 <=> g2<1
    if (l0 * l1 > 0.0f && g2 < 1.0f) {
        float inv = __builtin_amdgcn_rsqf(fmaxf(g2, 1e-60f));
        gx *= inv;
        gy *= inv;
    }
    // TAU = 1.0 -> energy_grad == gad
    f2v g; g.x = gx; g.y = gy;
    return g;
}

}  // namespace

// Fast path: n % 4 == 0. Grid-stride over the flat output in float4 units.
__global__ __launch_bounds__(BLOCK) void fw_sweep_kernel(
    const float* __restrict__ in, float* __restrict__ out, int n) {
    const float BETA = 0.1f;
    size_t n4 = (size_t)(n >> 2);            // float4s per n-float stream
    size_t total = 11 * n4;
    size_t stride = (size_t)gridDim.x * blockDim.x;   // 131072: ~2MB window

    const f2v* in2 = (const f2v*)in;
    const f4v* in4 = (const f4v*)in;
    f4v* out4 = (f4v*)out;

    for (size_t q = (size_t)blockIdx.x * blockDim.x + threadIdx.x;
         q < total; q += stride) {
        f4v res;
        if (q < n4) {
            // energy: 4 points per float4
            size_t t = q;
            f4v A = in4[2 * t], B = in4[2 * t + 1];
            res.x = energyf(pre(A.x, A.y));
            res.y = energyf(pre(A.z, A.w));
            res.z = energyf(pre(B.x, B.y));
            res.w = energyf(pre(B.z, B.w));
        } else if (q < 3 * n4) {
            // forces: 2 points per float4
            size_t t = q - n4;
            f4v A = in4[t];
            f2v f0 = forcef(pre(A.x, A.y));
            f2v f1 = forcef(pre(A.z, A.w));
            res.x = f0.x; res.y = f0.y; res.z = f1.x; res.w = f1.y;
        } else if (q < 5 * n4) {
            // energy_grad: 2 points per float4 (full pipeline)
            size_t t = q - 3 * n4;
            f4v A = in4[t];
            f2v g0 = gradf(pre(A.x, A.y));
            f2v g1 = gradf(pre(A.z, A.w));
            res.x = g0.x; res.y = g0.y; res.z = g1.x; res.w = g1.y;
        } else if (q < 9 * n4) {
            // hessian: 1 point per float4
            size_t t = q - 5 * n4;
            f2v p = in2[t];
            P pp = pre(p.x, p.y);
            res.x = 12.0f * pp.uu - 4.0f;
            res.y = BETA;
            res.z = BETA;
            res.w = 12.0f * pp.vv - 4.0f;
        } else if (q < 10 * n4) {
            // eigenval 0: 4 points per float4
            size_t t = q - 9 * n4;
            f4v A = in4[2 * t], B = in4[2 * t + 1];
            res.x = eigf(pre(A.x, A.y)).x;
            res.y = eigf(pre(A.z, A.w)).x;
            res.z = eigf(pre(B.x, B.y)).x;
            res.w = eigf(pre(B.z, B.w)).x;
        } else {
            // eigenval 1: 4 points per float4
            size_t t = q - 10 * n4;
            f4v A = in4[2 * t], B = in4[2 * t + 1];
            res.x = eigf(pre(A.x, A.y)).y;
            res.y = eigf(pre(A.z, A.w)).y;
            res.z = eigf(pre(B.x, B.y)).y;
            res.w = eigf(pre(B.z, B.w)).y;
        }
        out4[q] = res;
    }
}

// Fallback (n % 4 != 0): point-major scalar kernel, known-correct.
__global__ __launch_bounds__(BLOCK) void fw_energy_gad_scalar(
    const f2v* __restrict__ in, float* __restrict__ out, int n) {
    int i = blockIdx.x * blockDim.x + threadIdx.x;
    if (i >= n) return;
    const float BETA = 0.1f;
    f2v pt = in[i];
    P p = pre(pt.x, pt.y);
    f2v f = forcef(p);
    f2v e = eigf(p);
    f2v g = gradf(p);
    size_t N = (size_t)n;
    out[i] = energyf(p);
    ((f2v*)(out + N))[i] = f;
    ((f2v*)(out + 3 * N))[i] = g;
    out[5 * N + 4 * (size_t)i]     = 12.0f * p.uu - 4.0f;
    out[5 * N + 4 * (size_t)i + 1] = BETA;
    out[5 * N + 4 * (size_t)i + 2] = BETA;
    out[5 * N + 4 * (size_t)i + 3] = 12.0f * p.vv - 4.0f;
    out[9 * N + i]  = e.x;
    out[10 * N + i] = e.y;
}

extern "C" void kernel_launch(void* const* d_in, const int* in_sizes, int n_in,
                              void* d_out, int out_size, void* d_ws, size_t ws_size,
                              hipStream_t stream) {
    const float* in = (const float*)d_in[0];
    float* out = (float*)d_out;
    int n = in_sizes[0] / 2;   // B points, each (x, y)

    if ((n & 3) == 0) {
        size_t total = 11 * (size_t)(n >> 2);
        int grid = GRID;
        size_t need = (total + BLOCK - 1) / BLOCK;
        if ((size_t)grid > need) grid = (int)need;
        if (grid < 1) grid = 1;
        fw_sweep_kernel<<<grid, BLOCK, 0, stream>>>(in, out, n);
    } else {
        int grid = (n + BLOCK - 1) / BLOCK;
        fw_energy_gad_scalar<<<grid, BLOCK, 0, stream>>>((const f2v*)in, out, n);
    }
}